// Round 7
// baseline (398.240 us; speedup 1.0000x reference)
//
#include <hip/hip_runtime.h>
#include <math.h>

// ---------------- problem constants ----------------
constexpr int NN  = 32768;   // nodes
constexpr int BG  = 64;      // graphs
constexpr int NPG = 512;     // nodes per graph
constexpr int EG  = 524288;  // edges
constexpr int HH  = 4;       // heads
constexpr int FH  = 64;      // per-head dim
constexpr int CC  = 256;     // H*Fh
constexpr int FIN = 128;
constexpr int KP1 = 256;     // pool1 k
constexpr int KP2 = 128;     // pool2 k
constexpr int NS  = 4;       // register edge slots: fast path deg <= 64

__device__ inline float leaky02(float v) { return v > 0.0f ? v : 0.2f * v; }

// ---------------- GEMM v2: C[M,256] = A[M,K] @ B[K,256], fp32 -------------
// BM=64, BN=64, BK=16, 256 threads, 4x4 per-thread tile, register prefetch,
// LDS stride 68 (bank-conflict-free writes). Grid 512x4 = 2048 blocks (8/CU).
// Row-blocks XCD-swizzled: graph g -> XCD g&7 (matches gat_edge consumer).
// Epilogue: es/ed = per-head dot(h, a_src/a_dst); head = blockIdx.y.
__global__ __launch_bounds__(256, 8) void gemm_fp32_attn(const float* __restrict__ A,
                                                         const float* __restrict__ B,
                                                         float* __restrict__ Cm,
                                                         int K,
                                                         const float* __restrict__ a_src,
                                                         const float* __restrict__ a_dst,
                                                         float* __restrict__ es,
                                                         float* __restrict__ ed) {
    __shared__ float As[16][68];   // [k][row], stride 68: 2-way max on writes
    __shared__ float Bs[16][68];   // [k][col]
    const int t  = threadIdx.x;
    // swizzle: bx -> (graph on XCD bx&7, 64-row chunk)
    const int bx = blockIdx.x;                 // 0..511
    const int c  = bx & 7;
    const int s  = bx >> 3;                    // 0..63
    const int g  = c + ((s >> 3) << 3);        // graph
    const int bm = g * NPG + ((s & 7) << 6);   // row base
    const int bn = blockIdx.y * 64;
    // A staging: thread -> (row, 4 k's); coalesced 64B per 4-lane group
    const int arow = t >> 2;                   // 0..63
    const int akc  = (t & 3) << 2;             // 0,4,8,12
    // B staging: thread -> (k-row, 4 cols); fully coalesced
    const int brow = t >> 4;                   // 0..15
    const int bcol = (t & 15) << 2;            // 0..60
    // compute tile coords
    const int ty = t >> 4;                     // rows ty*4..+3
    const int tx = t & 15;                     // cols tx*4..+3

    const float* Aptr = A + (size_t)(bm + arow) * K + akc;
    const float* Bptr = B + (size_t)brow * CC + bn + bcol;

    float4 pa = *(const float4*)Aptr;
    float4 pb = *(const float4*)Bptr;

    float acc[4][4];
#pragma unroll
    for (int i = 0; i < 4; ++i)
#pragma unroll
        for (int j = 0; j < 4; ++j) acc[i][j] = 0.0f;

    for (int k0 = 0; k0 < K; k0 += 16) {
        __syncthreads();
        As[akc + 0][arow] = pa.x;
        As[akc + 1][arow] = pa.y;
        As[akc + 2][arow] = pa.z;
        As[akc + 3][arow] = pa.w;
        *(float4*)&Bs[brow][bcol] = pb;
        __syncthreads();
        if (k0 + 16 < K) {   // register prefetch of next tile (overlaps compute)
            pa = *(const float4*)(Aptr + k0 + 16);
            pb = *(const float4*)(Bptr + (size_t)(k0 + 16) * CC);
        }
#pragma unroll
        for (int k = 0; k < 16; ++k) {
            float av[4], bv[4];
            *(float4*)av = *(const float4*)&As[k][ty * 4];
            *(float4*)bv = *(const float4*)&Bs[k][tx * 4];
#pragma unroll
            for (int i = 0; i < 4; ++i)
#pragma unroll
                for (int j = 0; j < 4; ++j)
                    acc[i][j] = fmaf(av[i], bv[j], acc[i][j]);
        }
    }
#pragma unroll
    for (int i = 0; i < 4; ++i) {
        float4 v = make_float4(acc[i][0], acc[i][1], acc[i][2], acc[i][3]);
        *(float4*)(Cm + (size_t)(bm + ty * 4 + i) * CC + bn + tx * 4) = v;
    }

    // attention-coefficient epilogue (accumulators hold h rows; head=blockIdx.y)
    {
        const float4 as4 = *(const float4*)(a_src + bn + tx * 4);
        const float4 ad4 = *(const float4*)(a_dst + bn + tx * 4);
        const int head = blockIdx.y;
#pragma unroll
        for (int i = 0; i < 4; ++i) {
            float ps = acc[i][0] * as4.x + acc[i][1] * as4.y +
                       acc[i][2] * as4.z + acc[i][3] * as4.w;
            float pd = acc[i][0] * ad4.x + acc[i][1] * ad4.y +
                       acc[i][2] * ad4.z + acc[i][3] * ad4.w;
#pragma unroll
            for (int o = 8; o >= 1; o >>= 1) {
                ps += __shfl_down(ps, o, 16);
                pd += __shfl_down(pd, o, 16);
            }
            if (tx == 0) {
                es[(bm + ty * 4 + i) * HH + head] = ps;
                ed[(bm + ty * 4 + i) * HH + head] = pd;
            }
        }
    }
}

// ---------------- prep: zero cnt + w12 + T = tw2@c1w + bc2 = tb2@c1w -------
// blocks 0..127: zero cnt. block 128: w12/b12. blocks 129..192: T rows
// (4 rows x 64 cols per 256-thread block). block 193: bc2.
__global__ __launch_bounds__(256) void prep(int* __restrict__ cnt,
                                            const float* __restrict__ tw1,
                                            const float* __restrict__ sw2,
                                            const float* __restrict__ tb1,
                                            const float* __restrict__ sb2,
                                            float* __restrict__ w12,
                                            float* __restrict__ b12,
                                            const float* __restrict__ tw2,
                                            const float* __restrict__ c1w,
                                            const float* __restrict__ tb2,
                                            float* __restrict__ T,
                                            float* __restrict__ bc2) {
    const int b = blockIdx.x;
    const int t = threadIdx.x;
    if (b < 128) {
        cnt[b * 256 + t] = 0;
    } else if (b == 128) {
        float s = 0.0f;
        for (int o = 0; o < CC; ++o) s += tw1[t * CC + o] * sw2[o];
        w12[t] = s;
        if (t == 0) {
            float bb = 0.0f;
            for (int o = 0; o < CC; ++o) bb += tb1[o] * sw2[o];
            *b12 = bb + sb2[0];
        }
    } else if (b < 193) {
        const int r = (b - 129) * 4 + (t >> 6);   // 4 rows per block
        const int cth = t & 63;
        float s = 0.0f;
        for (int j = 0; j < CC; ++j) s = fmaf(tw2[r * CC + j], c1w[j * 64 + cth], s);
        T[r * 64 + cth] = s;
    } else if (t < 64) {
        float s = 0.0f;
        for (int j = 0; j < CC; ++j) s = fmaf(tb2[j], c1w[j * 64 + t], s);
        bc2[t] = s;
    }
}

// ---------------- fold_W: Wc = tw1@T, bc = tb1@T + bc2 + c1b --------------
// blocks 0..63: Wc rows (4 rows x 64 cols per block). block 64: bc.
__global__ __launch_bounds__(256) void fold_W(const float* __restrict__ tw1,
                                              const float* __restrict__ T,
                                              const float* __restrict__ tb1,
                                              const float* __restrict__ bc2,
                                              const float* __restrict__ c1b,
                                              float* __restrict__ Wc,
                                              float* __restrict__ bc) {
    const int b = blockIdx.x;
    const int t = threadIdx.x;
    if (b < 64) {
        const int r = b * 4 + (t >> 6);           // 4 rows per block
        const int cth = t & 63;
        float s = 0.0f;
        for (int j = 0; j < CC; ++j) s = fmaf(tw1[r * CC + j], T[j * 64 + cth], s);
        Wc[r * 64 + cth] = s;
    } else if (t < 64) {
        float s = 0.0f;
        for (int j = 0; j < CC; ++j) s = fmaf(tb1[j], T[j * 64 + t], s);
        bc[t] = s + bc2[t] + c1b[t];
    }
}

// ---------------- CSR build (by dst) ----------------
__global__ void csr_hist(const int* __restrict__ dst, int* cnt) {
    int e = blockIdx.x * 256 + threadIdx.x;
    if (e < EG) atomicAdd(&cnt[dst[e]], 1);
}
__global__ __launch_bounds__(1024) void csr_scan(const int* __restrict__ cnt,
                                                 int* __restrict__ rowp,
                                                 int* __restrict__ cur) {
    __shared__ int tmp[1024];
    const int t = threadIdx.x;
    const int base = t * 32;
    int local[32];
    int s = 0;
#pragma unroll
    for (int i = 0; i < 32; ++i) { local[i] = s; s += cnt[base + i]; }
    tmp[t] = s;
    __syncthreads();
    for (int o = 1; o < 1024; o <<= 1) {
        int v = (t >= o) ? tmp[t - o] : 0;
        __syncthreads();
        tmp[t] += v;
        __syncthreads();
    }
    int off = tmp[t] - s;  // exclusive prefix
#pragma unroll
    for (int i = 0; i < 32; ++i) {
        int p = off + local[i];
        rowp[base + i] = p;
        cur[base + i] = p;
    }
    if (t == 1023) rowp[NN] = off + s;
}
__global__ void csr_scatter(const int* __restrict__ src, const int* __restrict__ dst,
                            int* cur, int* __restrict__ esrc) {
    int e = blockIdx.x * 256 + threadIdx.x;
    if (e < EG) {
        int p = atomicAdd(&cur[dst[e]], 1);
        esrc[p] = src[e];
    }
}

// ---------------- fused GAT edge stage: softmax + aggregate + ELU ----------
// One wave per dst node, 4 waves/block, no barriers, XCD-swizzled.
__global__ __launch_bounds__(256) void gat_edge(const float* __restrict__ z,
                                                const int* __restrict__ rowp,
                                                const int* __restrict__ esrc,
                                                const float* __restrict__ es,
                                                const float* __restrict__ ed,
                                                const float* __restrict__ bias,
                                                float* __restrict__ out,
                                                const float* __restrict__ sw1,
                                                const float* __restrict__ sb1,
                                                const float* __restrict__ w12,
                                                const float* __restrict__ b12,
                                                float* __restrict__ sc1,
                                                float* __restrict__ sc2) {
    const int w = threadIdx.x >> 6;
    const int l = threadIdx.x & 63;
    const int b    = blockIdx.x;              // 0..8191
    const int xcd  = b & 7;
    const int slot = b >> 3;                  // 0..1023
    const int gph  = xcd + ((slot >> 7) << 3);
    const int d    = gph * NPG + ((slot & 127) << 2) + w;

    const int h  = l & 3;
    const int ei = l >> 2;
    const int h2 = l >> 4;
    const int beg = rowp[d];
    const int deg = rowp[d + 1] - beg;

    const float4 zv = *(const float4*)(z + (size_t)d * CC + 4 * l);
    float4 acc;

    if (deg <= 16 * NS) {
        // ---- phase A: register softmax ----
        const float edh = ed[d * HH + h];
        int   sidx[NS];
        float v[NS];
        float vmax = -INFINITY, eself = 0.0f;
        float vself = 0.0f;
        if (ei == 0) {
            vself = leaky02(es[d * HH + h] + edh);
            vmax = vself;
        }
#pragma unroll
        for (int j = 0; j < NS; ++j) {
            int i = ei + 16 * j;
            if (i < deg) {
                sidx[j] = esrc[beg + i];
                v[j] = leaky02(es[sidx[j] * HH + h] + edh);
                vmax = fmaxf(vmax, v[j]);
            }
        }
#pragma unroll
        for (int o = 4; o <= 32; o <<= 1) vmax = fmaxf(vmax, __shfl_xor(vmax, o));
        float dsum = 0.0f;
#pragma unroll
        for (int j = 0; j < NS; ++j) {
            int i = ei + 16 * j;
            if (i < deg) { v[j] = __expf(v[j] - vmax); dsum += v[j]; }
        }
        if (ei == 0) { eself = __expf(vself - vmax); dsum += eself; }
#pragma unroll
        for (int o = 4; o <= 32; o <<= 1) dsum += __shfl_xor(dsum, o);
        const float inv = 1.0f / (dsum + 1e-16f);
#pragma unroll
        for (int j = 0; j < NS; ++j) v[j] *= inv;   // normalized alpha
        eself *= inv;

        // ---- phase B: float4 aggregation ----
        float aself = __shfl(eself, h2);
        acc = make_float4(aself * zv.x, aself * zv.y, aself * zv.z, aself * zv.w);
#pragma unroll
        for (int j = 0; j < NS; ++j) {
            if (16 * j < deg) {
                for (int s = 0; s < 16; ++s) {
                    int i = 16 * j + s;
                    if (i >= deg) break;
                    int   srcn = __shfl(sidx[j], s * 4);
                    float a    = __shfl(v[j],    s * 4 + h2);
                    float4 zs  = *(const float4*)(z + (size_t)srcn * CC + 4 * l);
                    acc.x = fmaf(a, zs.x, acc.x);
                    acc.y = fmaf(a, zs.y, acc.y);
                    acc.z = fmaf(a, zs.z, acc.z);
                    acc.w = fmaf(a, zs.w, acc.w);
                }
            }
        }
    } else {
        // ---- generic slow path (never taken for the fixed input) ----
        const float edh = ed[d * HH + h];
        float vmax = (ei == 0) ? leaky02(es[d * HH + h] + edh) : -INFINITY;
        for (int i = ei; i < deg; i += 16)
            vmax = fmaxf(vmax, leaky02(es[esrc[beg + i] * HH + h] + edh));
#pragma unroll
        for (int o = 4; o <= 32; o <<= 1) vmax = fmaxf(vmax, __shfl_xor(vmax, o));
        float dsum = (ei == 0) ? __expf(leaky02(es[d * HH + h] + edh) - vmax) : 0.0f;
        for (int i = ei; i < deg; i += 16)
            dsum += __expf(leaky02(es[esrc[beg + i] * HH + h] + edh) - vmax);
#pragma unroll
        for (int o = 4; o <= 32; o <<= 1) dsum += __shfl_xor(dsum, o);
        const float inv = 1.0f / (dsum + 1e-16f);

        const float vmaxc = __shfl(vmax, h2);
        const float invc  = __shfl(inv,  h2);
        const float edh4  = ed[d * HH + h2];
        float a0 = __expf(leaky02(es[d * HH + h2] + edh4) - vmaxc) * invc;
        acc = make_float4(a0 * zv.x, a0 * zv.y, a0 * zv.z, a0 * zv.w);
        for (int i = 0; i < deg; ++i) {
            int srcn = esrc[beg + i];
            float a = __expf(leaky02(es[srcn * HH + h2] + edh4) - vmaxc) * invc;
            float4 zs = *(const float4*)(z + (size_t)srcn * CC + 4 * l);
            acc.x = fmaf(a, zs.x, acc.x);
            acc.y = fmaf(a, zs.y, acc.y);
            acc.z = fmaf(a, zs.z, acc.z);
            acc.w = fmaf(a, zs.w, acc.w);
        }
    }

    // ---- epilogue: bias + ELU (+ optional pooling scores) ----
    const float4 bv = *(const float4*)(bias + 4 * l);
    float4 o;
    o.x = acc.x + bv.x; o.x = o.x > 0.0f ? o.x : expm1f(o.x);
    o.y = acc.y + bv.y; o.y = o.y > 0.0f ? o.y : expm1f(o.y);
    o.z = acc.z + bv.z; o.z = o.z > 0.0f ? o.z : expm1f(o.z);
    o.w = acc.w + bv.w; o.w = o.w > 0.0f ? o.w : expm1f(o.w);
    *(float4*)(out + (size_t)d * CC + 4 * l) = o;

    if (sc1) {
        const float4 s1 = *(const float4*)(sw1 + 4 * l);
        const float4 s2 = *(const float4*)(w12 + 4 * l);
        float r1 = o.x * s1.x + o.y * s1.y + o.z * s1.z + o.w * s1.w;
        float r2 = o.x * s2.x + o.y * s2.y + o.z * s2.z + o.w * s2.w;
#pragma unroll
        for (int off = 32; off >= 1; off >>= 1) {
            r1 += __shfl_xor(r1, off);
            r2 += __shfl_xor(r2, off);
        }
        if (l == 0) {
            sc1[d] = r1 + sb1[0];
            sc2[d] = r2 + b12[0];
        }
    }
}

// ---------------- fused pooling + folded head (one block per graph) -------
// topk1/topk2 -> masked float4 mean -> relu(mean@Wc+bc) -> @c2w+c2b -> lsm
__global__ __launch_bounds__(512) void pool_head(const float* __restrict__ feat,
                                                 const float* __restrict__ sc1,
                                                 const float* __restrict__ sc2,
                                                 const float* __restrict__ Wc,
                                                 const float* __restrict__ bc,
                                                 const float* __restrict__ c2w,
                                                 const float* __restrict__ c2b,
                                                 float* __restrict__ out) {
    __shared__ float s[NPG];
    __shared__ unsigned char keep[NPG];
    __shared__ float vbuf[8][CC];
    __shared__ float v0[CC];
    __shared__ float part[8][64];
    __shared__ float v2[64];
    const int g = blockIdx.x;
    const int i = threadIdx.x;

    // ---- top-k1 (rank counting; lower index wins ties) ----
    float my = sc1[g * NPG + i];
    s[i] = my;
    __syncthreads();
    int rank = 0;
    for (int j = 0; j < NPG; ++j) {
        float sj = s[j];
        rank += (sj > my) || (sj == my && j < i);
    }
    int k1 = rank < KP1;
    __syncthreads();
    // ---- top-k2 restricted to k1 set ----
    float my2 = k1 ? sc2[g * NPG + i] : -INFINITY;
    s[i] = my2;
    __syncthreads();
    rank = 0;
    for (int j = 0; j < NPG; ++j) {
        float sj = s[j];
        rank += (sj > my2) || (sj == my2 && j < i);
    }
    keep[i] = (unsigned char)(k1 && rank < KP2);
    __syncthreads();

    // ---- masked mean, float4: thread = (rowgroup r, ch4 c4) ----
    const int r = i >> 6, c4 = i & 63;
    float4 acc = make_float4(0.0f, 0.0f, 0.0f, 0.0f);
    const float4* f4 = (const float4*)(feat + (size_t)g * NPG * CC);
    for (int j = r; j < NPG; j += 8) {
        if (keep[j]) {
            float4 v = f4[j * 64 + c4];
            acc.x += v.x; acc.y += v.y; acc.z += v.z; acc.w += v.w;
        }
    }
    vbuf[r][c4 * 4 + 0] = acc.x;
    vbuf[r][c4 * 4 + 1] = acc.y;
    vbuf[r][c4 * 4 + 2] = acc.z;
    vbuf[r][c4 * 4 + 3] = acc.w;
    __syncthreads();
    if (i < CC) {
        float t = 0.0f;
#pragma unroll
        for (int q = 0; q < 8; ++q) t += vbuf[q][i];
        v0[i] = t * (1.0f / KP2);
    }
    __syncthreads();

    // ---- u = relu(v0 @ Wc + bc), split j-sum 8 ways ----
    {
        const int q = i >> 6, cth = i & 63;
        float p = 0.0f;
        for (int j = q * 32; j < q * 32 + 32; ++j)
            p = fmaf(v0[j], Wc[j * 64 + cth], p);
        part[q][cth] = p;
    }
    __syncthreads();
    if (i < 64) {
        float u = bc[i];
#pragma unroll
        for (int q = 0; q < 8; ++q) u += part[q][i];
        v2[i] = fmaxf(u, 0.0f);
    }
    __syncthreads();
    if (i < 2) {
        float o = c2b[i];
        for (int j = 0; j < 64; ++j) o = fmaf(v2[j], c2w[j * 2 + i], o);
        s[i] = o;
    }
    __syncthreads();
    if (i == 0) {
        float a = s[0], bq = s[1];
        float mx = fmaxf(a, bq);
        float lse = mx + logf(expf(a - mx) + expf(bq - mx));
        out[g * 2 + 0] = a - lse;
        out[g * 2 + 1] = bq - lse;
    }
}

// ---------------- launcher ----------------
extern "C" void kernel_launch(void* const* d_in, const int* in_sizes, int n_in,
                              void* d_out, int out_size, void* d_ws, size_t ws_size,
                              hipStream_t stream) {
    const float* x      = (const float*)d_in[0];
    const int*   ei     = (const int*)d_in[1];
    const int*   src    = ei;
    const int*   dst    = ei + EG;
    const float* W1     = (const float*)d_in[3];
    const float* a_src1 = (const float*)d_in[4];
    const float* a_dst1 = (const float*)d_in[5];
    const float* b1     = (const float*)d_in[6];
    const float* W2     = (const float*)d_in[7];
    const float* a_src2 = (const float*)d_in[8];
    const float* a_dst2 = (const float*)d_in[9];
    const float* b2     = (const float*)d_in[10];
    const float* p1_sw  = (const float*)d_in[11];
    const float* p1_sb  = (const float*)d_in[12];
    const float* p1_tw  = (const float*)d_in[13];
    const float* p1_tb  = (const float*)d_in[14];
    const float* p2_sw  = (const float*)d_in[15];
    const float* p2_sb  = (const float*)d_in[16];
    const float* p2_tw  = (const float*)d_in[17];
    const float* p2_tb  = (const float*)d_in[18];
    const float* c1w    = (const float*)d_in[19];
    const float* c1b    = (const float*)d_in[20];
    const float* c2w    = (const float*)d_in[21];
    const float* c2b    = (const float*)d_in[22];
    float* out = (float*)d_out;

    // workspace layout (floats)
    float* ws   = (float*)d_ws;
    float* z    = ws;                          // N*C
    float* feat = z + (size_t)NN * CC;         // N*C
    float* es   = feat + (size_t)NN * CC;      // N*H
    float* ed   = es + NN * HH;                // N*H
    int*   cnt  = (int*)(ed + NN * HH);        // N
    int*   rowp = cnt + NN;                    // N+1
    int*   cur  = rowp + NN + 1;               // N
    int*   esrc = cur + NN;                    // E
    float* sc1  = (float*)(esrc + EG);         // N
    float* sc2  = sc1 + NN;                    // N
    float* w12  = sc2 + NN;                    // C
    float* b12  = w12 + CC;                    // 1 (padded to 64)
    float* T    = b12 + 64;                    // 256*64
    float* Wc   = T + CC * 64;                 // 256*64
    float* bc2  = Wc + CC * 64;                // 64
    float* bcv  = bc2 + 64;                    // 64

    // ---- prep (cnt zero + w12 + T + bc2) and CSR build ----
    prep<<<194, 256, 0, stream>>>(cnt, p1_tw, p2_sw, p1_tb, p2_sb, w12, b12,
                                  p2_tw, c1w, p2_tb, T, bc2);
    csr_hist<<<(EG + 255) / 256, 256, 0, stream>>>(dst, cnt);
    csr_scan<<<1, 1024, 0, stream>>>(cnt, rowp, cur);
    csr_scatter<<<(EG + 255) / 256, 256, 0, stream>>>(src, dst, cur, esrc);
    fold_W<<<65, 256, 0, stream>>>(p1_tw, T, p1_tb, bc2, c1b, Wc, bcv);

    dim3 gemm_grid(NN / 64, CC / 64);

    // ---- GAT layer 1 ----
    gemm_fp32_attn<<<gemm_grid, 256, 0, stream>>>(x, W1, z, FIN,
                                                  a_src1, a_dst1, es, ed);
    gat_edge<<<NN / 4, 256, 0, stream>>>(z, rowp, esrc, es, ed, b1, feat,
                                         nullptr, nullptr, nullptr, nullptr,
                                         nullptr, nullptr);

    // ---- GAT layer 2 (pooling scores fused into epilogue) ----
    gemm_fp32_attn<<<gemm_grid, 256, 0, stream>>>(feat, W2, z, CC,
                                                  a_src2, a_dst2, es, ed);
    gat_edge<<<NN / 4, 256, 0, stream>>>(z, rowp, esrc, es, ed, b2, feat,
                                         p1_sw, p1_sb, w12, b12, sc1, sc2);

    // ---- fused pooling + folded head ----
    pool_head<<<BG, 512, 0, stream>>>(feat, sc1, sc2, Wc, bcv, c2w, c2b, out);
}